// Round 2
// baseline (580.623 us; speedup 1.0000x reference)
//
#include <hip/hip_runtime.h>

namespace {
constexpr int kB = 256;
constexpr int kS = 2048;
constexpr int kV = 10;
constexpr int kE = 32;
constexpr int kH = 64;
constexpr int kO = 10;
constexpr int kT = 16;      // steps per tile
constexpr int kPad = 68;    // LDS row stride in floats (272 B, 16B-aligned)
constexpr int kTiles = kS / kT;   // 128
// Fold tanh's 2x and log2(e) into weights: s = kC*(xw + h.Wh + b), e^{2p} = 2^s
constexpr float kC = 2.885390081777927f;   // 2*log2(e)

__device__ __forceinline__ float step_tanh(float s) {
    s = __builtin_amdgcn_fmed3f(s, -26.f, 26.f);
    float e = __builtin_amdgcn_exp2f(s);
    float r = __builtin_amdgcn_rcpf(e + 1.f);
    return fmaf(-2.f, r, 1.f);              // tanh = 1 - 2/(e^{2p}+1)
}

// 16 recurrence steps, dual-pipe broadcast:
//   k=0..31  : v_readlane -> SGPR (VALU pipe), feeds first-half FMAs
//   k=32..63 : 8x ds_read_b128 of the just-written history row (DS pipe,
//              uniform-address broadcast, conflict-free). Issued at step head;
//              ~120cy latency hides under the 32 readlanes + 32 first-half
//              FMAs (~130cy of VALU issue) before first consumption.
// Single wave -> in-order DS pipe -> the read of row tl-1 issued after its
// ds_write is guaranteed to see the data (same guarantee R0 relied on).
// Arithmetic order identical to the all-readlane version (k ascending,
// 4 accumulator chains) -> bit-identical output.
__device__ __forceinline__ float do_steps(float h, float* __restrict__ cur,
                                          const float* __restrict__ prevLast,
                                          const float* __restrict__ xw,
                                          const float* __restrict__ whc, int l)
{
    #pragma unroll
    for (int tl = 0; tl < kT; ++tl) {
        const float* hrow = (tl == 0) ? prevLast : (cur + (tl - 1) * kPad);
        const float4* hp = reinterpret_cast<const float4*>(hrow + 32);
        float4 q[8];
        #pragma unroll
        for (int c = 0; c < 8; ++c) q[c] = hp[c];   // DS pipe: h[32..63] bcast
        __builtin_amdgcn_sched_barrier(0);          // keep DS issue at step head
        const int hb = __float_as_int(h);
        float a0 = xw[tl], a1 = 0.f, a2 = 0.f, a3 = 0.f;
        #pragma unroll
        for (int k = 0; k < 32; k += 4) {           // VALU pipe: h[0..31] bcast
            const float h0 = __int_as_float(__builtin_amdgcn_readlane(hb, k + 0));
            const float h1 = __int_as_float(__builtin_amdgcn_readlane(hb, k + 1));
            const float h2 = __int_as_float(__builtin_amdgcn_readlane(hb, k + 2));
            const float h3 = __int_as_float(__builtin_amdgcn_readlane(hb, k + 3));
            a0 = fmaf(h0, whc[k + 0], a0);   // SGPR x VGPR + VGPR
            a1 = fmaf(h1, whc[k + 1], a1);
            a2 = fmaf(h2, whc[k + 2], a2);
            a3 = fmaf(h3, whc[k + 3], a3);
        }
        // second half: LDS-broadcast h, both FMA operands in VGPRs
        #pragma unroll
        for (int c = 0; c < 8; ++c) {
            a0 = fmaf(q[c].x, whc[32 + 4 * c + 0], a0);
            a1 = fmaf(q[c].y, whc[32 + 4 * c + 1], a1);
            a2 = fmaf(q[c].z, whc[32 + 4 * c + 2], a2);
            a3 = fmaf(q[c].w, whc[32 + 4 * c + 3], a3);
        }
        h = step_tanh((a0 + a1) + (a2 + a3));
        cur[tl * kPad + l] = h;   // history row: logits input + next step's bcast
    }
    return h;
}

__device__ __forceinline__ void do_logits(const float* __restrict__ hb,
                                          const float (* __restrict__ WdT)[kPad],
                                          const float* __restrict__ bdL,
                                          float* __restrict__ out, int obase, int l)
{
    #pragma unroll
    for (int r = 0; r < 3; ++r) {
        int f = r * 64 + l;                  // flat (t_local, o), 160 total
        if (f < kT * kO) {
            int tl = f / kO;
            int o  = f - tl * kO;
            const float4* hb4 = reinterpret_cast<const float4*>(hb + tl * kPad);
            const float4* wd4 = reinterpret_cast<const float4*>(&WdT[o][0]);
            float a0 = bdL[o], a1 = 0.f, a2 = 0.f, a3 = 0.f;
            #pragma unroll
            for (int c = 0; c < kH / 4; ++c) {
                float4 h4 = hb4[c];
                float4 w4 = wd4[c];
                a0 = fmaf(h4.x, w4.x, a0);
                a1 = fmaf(h4.y, w4.y, a1);
                a2 = fmaf(h4.z, w4.z, a2);
                a3 = fmaf(h4.w, w4.w, a3);
            }
            out[obase + f] = (a0 + a1) + (a2 + a3);   // coalesced
        }
    }
}

// Wave 0: serial recurrence (latency-critical). Wave 1: logits for the
// previous tile out of the double-buffered h history. One barrier per tile;
// wave 1's per-tile work is ~1/8 of wave 0's, so wave 0 never stalls on it.
__global__ __launch_bounds__(128, 1)
void rnn_fused(const int* __restrict__ num1, const int* __restrict__ num2,
               const float* __restrict__ embed, const float* __restrict__ Wx,
               const float* __restrict__ Wh, const float* __restrict__ bias,
               const float* __restrict__ Wd, const float* __restrict__ bd,
               float* __restrict__ out)
{
    const int row = blockIdx.x;   // one sequence per block
    const int tid = threadIdx.x;
    const int w   = tid >> 6;     // 0 = recurrence wave, 1 = logits wave
    const int l   = tid & 63;     // lane owns hidden unit l (wave 0)

    __shared__ __align__(16) float TT[kV * kV][kH];     // kC*(xw+b), 100 rows
    __shared__ __align__(16) float hbuf[2][kT][kPad];   // double-buffered h history
    __shared__ __align__(16) float WdT[kO][kPad];
    __shared__ float bdL[kO];

    float whc[kH];                // wave 0: kC * Wh column l (full K)
    float xw[kT];
    float h = 0.f;
    int idx_next = 0;
    const int lane16 = l & 15;
    const int nb = row * kS;
    const int orow = row * (kS * kO);

    if (w == 0) {
        // ---- one-time setup: input-projection table + Wh column ----
        float wxc[2 * kE];
        #pragma unroll
        for (int k = 0; k < 2 * kE; ++k) wxc[k] = Wx[k * kH + l];  // Wx column l
        float bj = bias[l];
        float t1[kV], t2[kV];
        #pragma unroll
        for (int v = 0; v < kV; ++v) {
            float a0 = 0.f, a1 = 0.f;
            #pragma unroll
            for (int k = 0; k < kE; ++k) {
                float e = embed[v * kE + k];   // lane-uniform -> s_load
                a0 = fmaf(e, wxc[k], a0);
                a1 = fmaf(e, wxc[kE + k], a1);
            }
            t1[v] = a0; t2[v] = a1;
        }
        #pragma unroll
        for (int v1 = 0; v1 < kV; ++v1)
            #pragma unroll
            for (int v2 = 0; v2 < kV; ++v2)
                TT[v1 * kV + v2][l] = kC * (t1[v1] + t2[v2] + bj);
        #pragma unroll
        for (int k = 0; k < kH; ++k) whc[k] = kC * Wh[k * kH + l];
        hbuf[1][kT - 1][l] = 0.f;   // h_{-1}=0: tile 0 broadcast reads this row
        idx_next = num1[nb + lane16] * kV + num2[nb + lane16];   // tile 0 idx
    } else {
        #pragma unroll
        for (int o = 0; o < kO; ++o) WdT[o][l] = Wd[l * kO + o];
        if (l < kO) bdL[l] = bd[l];
    }
    __syncthreads();

    for (int ti = 0; ti < kTiles; ++ti) {
        if (w == 0) {
            const int idxv = idx_next;
            if (ti + 1 < kTiles) {
                int tt = nb + (ti + 1) * kT + lane16;
                idx_next = num1[tt] * kV + num2[tt];   // prefetch next tile idx
            }
            #pragma unroll
            for (int tl = 0; tl < kT; ++tl) {
                int sidx = __builtin_amdgcn_readlane(idxv, tl);   // uniform
                xw[tl] = TT[sidx][l];
            }
            h = do_steps(h, &hbuf[ti & 1][0][0], &hbuf[(ti & 1) ^ 1][kT - 1][0],
                         xw, whc, l);
        } else if (ti > 0) {
            do_logits(&hbuf[(ti - 1) & 1][0][0], WdT, bdL, out,
                      orow + (ti - 1) * kT * kO, l);
        }
        __syncthreads();   // publish tile ti history / retire tile ti-1 reads
    }
    if (w == 1)
        do_logits(&hbuf[(kTiles - 1) & 1][0][0], WdT, bdL, out,
                  orow + (kS - kT) * kO, l);
}
} // namespace

extern "C" void kernel_launch(void* const* d_in, const int* in_sizes, int n_in,
                              void* d_out, int out_size, void* d_ws, size_t ws_size,
                              hipStream_t stream) {
    (void)in_sizes; (void)n_in; (void)d_ws; (void)ws_size; (void)out_size;
    rnn_fused<<<dim3(kB), dim3(128), 0, stream>>>(
        (const int*)d_in[0], (const int*)d_in[1],
        (const float*)d_in[2], (const float*)d_in[3],
        (const float*)d_in[4], (const float*)d_in[5],
        (const float*)d_in[6], (const float*)d_in[7],
        (float*)d_out);
}

// Round 3
// 492.840 us; speedup vs baseline: 1.1781x; 1.1781x over previous
//
#include <hip/hip_runtime.h>

namespace {
typedef float v2f __attribute__((ext_vector_type(2)));
constexpr int kB = 256;
constexpr int kS = 2048;
constexpr int kV = 10;
constexpr int kE = 32;
constexpr int kH = 64;
constexpr int kO = 10;
constexpr int kT = 16;      // steps per tile
constexpr int kPad = 68;    // LDS row stride in floats (272 B, 16B-aligned)
constexpr int kTiles = kS / kT;   // 128
// Fold tanh's 2x and log2(e) into weights: s = kC*(xw + h.Wh + b), e^{2p} = 2^s
constexpr float kC = 2.885390081777927f;   // 2*log2(e)

__device__ __forceinline__ float step_tanh(float s) {
    s = __builtin_amdgcn_fmed3f(s, -26.f, 26.f);
    float e = __builtin_amdgcn_exp2f(s);
    float r = __builtin_amdgcn_rcpf(e + 1.f);
    return fmaf(-2.f, r, 1.f);              // tanh = 1 - 2/(e^{2p}+1)
}

__device__ __forceinline__ void do_logits(const float* __restrict__ hb,
                                          const float (* __restrict__ WdT)[kPad],
                                          const float* __restrict__ bdL,
                                          float* __restrict__ out, int obase, int l)
{
    #pragma unroll
    for (int r = 0; r < 3; ++r) {
        int f = r * 64 + l;                  // flat (t_local, o), 160 total
        if (f < kT * kO) {
            int tl = f / kO;
            int o  = f - tl * kO;
            const float4* hb4 = reinterpret_cast<const float4*>(hb + tl * kPad);
            const float4* wd4 = reinterpret_cast<const float4*>(&WdT[o][0]);
            float a0 = bdL[o], a1 = 0.f, a2 = 0.f, a3 = 0.f;
            #pragma unroll
            for (int c = 0; c < kH / 4; ++c) {
                float4 h4 = hb4[c];
                float4 w4 = wd4[c];
                a0 = fmaf(h4.x, w4.x, a0);
                a1 = fmaf(h4.y, w4.y, a1);
                a2 = fmaf(h4.z, w4.z, a2);
                a3 = fmaf(h4.w, w4.w, a3);
            }
            out[obase + f] = (a0 + a1) + (a2 + a3);   // coalesced
        }
    }
}

// Wave 0: serial recurrence. Single-wave issue cadence is ~1 instr / 4 cy, so
// the chain wave's wall time ~= 4 * instruction_count; this version minimizes
// instructions: full-h LDS broadcast (16x ds_read_b128, uniform address =
// conflict-free bcast) + packed v_pk_fma_f32 (float2 math, 32 packed FMAs for
// the 64 MACs). The tl-loop is NOT unrolled (<1 KB hot loop: I-fetch hedge).
// Wave 1: logits for the previous tile from the double-buffered h history.
__global__ __launch_bounds__(128, 1)
void rnn_fused(const int* __restrict__ num1, const int* __restrict__ num2,
               const float* __restrict__ embed, const float* __restrict__ Wx,
               const float* __restrict__ Wh, const float* __restrict__ bias,
               const float* __restrict__ Wd, const float* __restrict__ bd,
               float* __restrict__ out)
{
    const int row = blockIdx.x;   // one sequence per block
    const int tid = threadIdx.x;
    const int w   = tid >> 6;     // 0 = recurrence wave, 1 = logits wave
    const int l   = tid & 63;     // lane owns hidden unit l (wave 0)

    __shared__ __align__(16) float TT[kV * kV][kH];     // kC*(xw+b), 100 rows
    __shared__ __align__(16) float hbuf[2][kT][kPad];   // double-buffered h history
    __shared__ __align__(16) float WdT[kO][kPad];
    __shared__ float bdL[kO];

    v2f whc2[kH / 2];             // wave 0: kC * Wh column l as packed pairs
    float h = 0.f;
    int idx_next = 0;
    const int lane16 = l & 15;
    const int nb = row * kS;
    const int orow = row * (kS * kO);

    if (w == 0) {
        // ---- one-time setup: input-projection table + Wh column ----
        float wxc[2 * kE];
        #pragma unroll
        for (int k = 0; k < 2 * kE; ++k) wxc[k] = Wx[k * kH + l];  // Wx column l
        float bj = bias[l];
        float t1[kV], t2[kV];
        #pragma unroll
        for (int v = 0; v < kV; ++v) {
            float a0 = 0.f, a1 = 0.f;
            #pragma unroll
            for (int k = 0; k < kE; ++k) {
                float e = embed[v * kE + k];   // lane-uniform -> s_load
                a0 = fmaf(e, wxc[k], a0);
                a1 = fmaf(e, wxc[kE + k], a1);
            }
            t1[v] = a0; t2[v] = a1;
        }
        #pragma unroll
        for (int v1 = 0; v1 < kV; ++v1)
            #pragma unroll
            for (int v2 = 0; v2 < kV; ++v2)
                TT[v1 * kV + v2][l] = kC * (t1[v1] + t2[v2] + bj);
        #pragma unroll
        for (int i = 0; i < kH / 2; ++i) {
            v2f t;
            t.x = kC * Wh[(2 * i)     * kH + l];
            t.y = kC * Wh[(2 * i + 1) * kH + l];
            whc2[i] = t;
        }
        hbuf[1][kT - 1][l] = 0.f;   // h_{-1}=0: tile 0 broadcast reads this row
        idx_next = num1[nb + lane16] * kV + num2[nb + lane16];   // tile 0 idx
        __builtin_amdgcn_s_setprio(1);   // favor the chain wave in arbitration
    } else {
        #pragma unroll
        for (int o = 0; o < kO; ++o) WdT[o][l] = Wd[l * kO + o];
        if (l < kO) bdL[l] = bd[l];
    }
    __syncthreads();

    const float* prevRow = &hbuf[1][kT - 1][0];   // rolling h_{t-1} row

    for (int ti = 0; ti < kTiles; ++ti) {
        if (w == 0) {
            const int idxv = idx_next;
            if (ti + 1 < kTiles) {
                int tt = nb + (ti + 1) * kT + lane16;
                idx_next = num1[tt] * kV + num2[tt];   // prefetch next tile idx
            }
            float* curBase = &hbuf[ti & 1][0][0];
            #pragma unroll 1
            for (int tl = 0; tl < kT; ++tl) {
                const int sidx = __builtin_amdgcn_readlane(idxv, tl); // dyn lane
                const float xwv = TT[sidx][l];       // ds_read, consumed late
                const float4* hq = reinterpret_cast<const float4*>(prevRow);
                float4 q[16];
                #pragma unroll
                for (int c = 0; c < 16; ++c) q[c] = hq[c];   // 16x b128 bcast
                __builtin_amdgcn_sched_barrier(0);           // loads at step head
                v2f pl[4], ph[4];
                #pragma unroll
                for (int i = 0; i < 4; ++i) { pl[i] = (v2f){0.f, 0.f};
                                              ph[i] = (v2f){0.f, 0.f}; }
                #pragma unroll
                for (int c = 0; c < 16; ++c) {
                    v2f lo; lo.x = q[c].x; lo.y = q[c].y;
                    v2f hi; hi.x = q[c].z; hi.y = q[c].w;
                    pl[c & 3] = lo * whc2[2 * c]     + pl[c & 3];  // v_pk_fma_f32
                    ph[c & 3] = hi * whc2[2 * c + 1] + ph[c & 3];
                }
                v2f t = ((pl[0] + pl[1]) + (pl[2] + pl[3]))
                      + ((ph[0] + ph[1]) + (ph[2] + ph[3]));
                h = step_tanh((t.x + t.y) + xwv);
                float* wr = curBase + tl * kPad;
                wr[l] = h;                 // history row (logits + next bcast)
                prevRow = wr;
            }
        } else if (ti > 0) {
            do_logits(&hbuf[(ti - 1) & 1][0][0], WdT, bdL, out,
                      orow + (ti - 1) * kT * kO, l);
        }
        __syncthreads();   // publish tile ti history / retire tile ti-1 reads
    }
    if (w == 1)
        do_logits(&hbuf[(kTiles - 1) & 1][0][0], WdT, bdL, out,
                  orow + (kS - kT) * kO, l);
}
} // namespace

extern "C" void kernel_launch(void* const* d_in, const int* in_sizes, int n_in,
                              void* d_out, int out_size, void* d_ws, size_t ws_size,
                              hipStream_t stream) {
    (void)in_sizes; (void)n_in; (void)d_ws; (void)ws_size; (void)out_size;
    rnn_fused<<<dim3(kB), dim3(128), 0, stream>>>(
        (const int*)d_in[0], (const int*)d_in[1],
        (const float*)d_in[2], (const float*)d_in[3],
        (const float*)d_in[4], (const float*)d_in[5],
        (const float*)d_in[6], (const float*)d_in[7],
        (float*)d_out);
}

// Round 4
// 486.097 us; speedup vs baseline: 1.1945x; 1.0139x over previous
//
#include <hip/hip_runtime.h>

namespace {
typedef float v2f __attribute__((ext_vector_type(2)));
constexpr int kB = 256;
constexpr int kS = 2048;
constexpr int kV = 10;
constexpr int kE = 32;
constexpr int kH = 64;
constexpr int kO = 10;
constexpr int kT = 16;      // steps per tile
constexpr int kPad = 68;    // LDS row stride in floats (272 B, 16B-aligned)
constexpr int kTiles = kS / kT;   // 128
// Fold tanh's 2x and log2(e) into weights: s = kC*(xw + h.Wh + b), e^{2p} = 2^s
constexpr float kC = 2.885390081777927f;   // 2*log2(e)

__device__ __forceinline__ float step_tanh(float s) {
    s = __builtin_amdgcn_fmed3f(s, -26.f, 26.f);
    float e = __builtin_amdgcn_exp2f(s);
    float r = __builtin_amdgcn_rcpf(e + 1.f);
    return fmaf(-2.f, r, 1.f);              // tanh = 1 - 2/(e^{2p}+1)
}

__device__ __forceinline__ void do_logits(const float* __restrict__ hb,
                                          const float (* __restrict__ WdT)[kPad],
                                          const float* __restrict__ bdL,
                                          float* __restrict__ out, int obase, int l)
{
    #pragma unroll
    for (int r = 0; r < 3; ++r) {
        int f = r * 64 + l;                  // flat (t_local, o), 160 total
        if (f < kT * kO) {
            int tl = f / kO;
            int o  = f - tl * kO;
            const float4* hb4 = reinterpret_cast<const float4*>(hb + tl * kPad);
            const float4* wd4 = reinterpret_cast<const float4*>(&WdT[o][0]);
            float a0 = bdL[o], a1 = 0.f, a2 = 0.f, a3 = 0.f;
            #pragma unroll
            for (int c = 0; c < kH / 4; ++c) {
                float4 h4 = hb4[c];
                float4 w4 = wd4[c];
                a0 = fmaf(h4.x, w4.x, a0);
                a1 = fmaf(h4.y, w4.y, a1);
                a2 = fmaf(h4.z, w4.z, a2);
                a3 = fmaf(h4.w, w4.w, a3);
            }
            out[obase + f] = (a0 + a1) + (a2 + a3);   // coalesced
        }
    }
}

// quad i (k = 4i..4i+3): lo pair -> p0/p2, hi pair -> p1/p3 (4 acc chains)
#define ACCQ(Q, i)                                                          \
    do {                                                                    \
        v2f lo_; lo_.x = (Q).x; lo_.y = (Q).y;                              \
        v2f hi_; hi_.x = (Q).z; hi_.y = (Q).w;                              \
        if (((i) & 1) == 0) { p0 = lo_ * whc2[2 * (i)]     + p0;            \
                              p1 = hi_ * whc2[2 * (i) + 1] + p1; }          \
        else                { p2 = lo_ * whc2[2 * (i)]     + p2;            \
                              p3 = hi_ * whc2[2 * (i) + 1] + p3; }          \
    } while (0)

// Wave 0: serial recurrence. Explicit ping-pong pipeline: two 4-quad LDS
// broadcast buffers (uniform-address ds_read_b128 = conflict-free bcast),
// chunk n+1's loads issue while chunk n's packed FMAs run. Keeps live regs
// small (whc2 64 + A/B 32 + accs) so the allocator never squeezes the
// schedule (R3 lesson: q[16]+whc2 demanded >128 regs, allocator fell back
// to a serialized schedule at VGPR_Count=88).
// Wave 1: logits for the previous tile from the double-buffered h history.
__global__ __launch_bounds__(128, 1)
void rnn_fused(const int* __restrict__ num1, const int* __restrict__ num2,
               const float* __restrict__ embed, const float* __restrict__ Wx,
               const float* __restrict__ Wh, const float* __restrict__ bias,
               const float* __restrict__ Wd, const float* __restrict__ bd,
               float* __restrict__ out)
{
    const int row = blockIdx.x;   // one sequence per block
    const int tid = threadIdx.x;
    const int w   = tid >> 6;     // 0 = recurrence wave, 1 = logits wave
    const int l   = tid & 63;     // lane owns hidden unit l (wave 0)

    __shared__ __align__(16) float TT[kV * kV][kH];     // kC*(xw+b), 100 rows
    __shared__ __align__(16) float hbuf[2][kT][kPad];   // double-buffered h history
    __shared__ __align__(16) float WdT[kO][kPad];
    __shared__ float bdL[kO];

    v2f whc2[kH / 2];             // wave 0: kC * Wh column l as packed pairs
    float h = 0.f;
    int idx_next = 0;
    const int lane16 = l & 15;
    const int nb = row * kS;
    const int orow = row * (kS * kO);

    if (w == 0) {
        // ---- one-time setup: input-projection table + Wh column ----
        float wxc[2 * kE];
        #pragma unroll
        for (int k = 0; k < 2 * kE; ++k) wxc[k] = Wx[k * kH + l];  // Wx column l
        float bj = bias[l];
        float t1[kV], t2[kV];
        #pragma unroll
        for (int v = 0; v < kV; ++v) {
            float a0 = 0.f, a1 = 0.f;
            #pragma unroll
            for (int k = 0; k < kE; ++k) {
                float e = embed[v * kE + k];   // lane-uniform -> s_load
                a0 = fmaf(e, wxc[k], a0);
                a1 = fmaf(e, wxc[kE + k], a1);
            }
            t1[v] = a0; t2[v] = a1;
        }
        #pragma unroll
        for (int v1 = 0; v1 < kV; ++v1)
            #pragma unroll
            for (int v2 = 0; v2 < kV; ++v2)
                TT[v1 * kV + v2][l] = kC * (t1[v1] + t2[v2] + bj);
        #pragma unroll
        for (int i = 0; i < kH / 2; ++i) {
            v2f t;
            t.x = kC * Wh[(2 * i)     * kH + l];
            t.y = kC * Wh[(2 * i + 1) * kH + l];
            whc2[i] = t;
        }
        hbuf[1][kT - 1][l] = 0.f;   // h_{-1}=0: tile 0 broadcast reads this row
        idx_next = num1[nb + lane16] * kV + num2[nb + lane16];   // tile 0 idx
        __builtin_amdgcn_s_setprio(1);   // favor the chain wave in arbitration
    } else {
        #pragma unroll
        for (int o = 0; o < kO; ++o) WdT[o][l] = Wd[l * kO + o];
        if (l < kO) bdL[l] = bd[l];
    }
    __syncthreads();

    const float* prevRow = &hbuf[1][kT - 1][0];   // rolling h_{t-1} row

    for (int ti = 0; ti < kTiles; ++ti) {
        if (w == 0) {
            const int idxv = idx_next;
            if (ti + 1 < kTiles) {
                int tt = nb + (ti + 1) * kT + lane16;
                idx_next = num1[tt] * kV + num2[tt];   // prefetch next tile idx
            }
            float* curBase = &hbuf[ti & 1][0][0];
            #pragma unroll 1
            for (int tl = 0; tl < kT; ++tl) {
                const int sidx = __builtin_amdgcn_readlane(idxv, tl); // dyn lane
                const float xwv = TT[sidx][l];   // issued first, returns first
                const float4* hq = reinterpret_cast<const float4*>(prevRow);
                // stage 0: fill both ping-pong buffers (quads 0..7)
                float4 A0 = hq[0], A1 = hq[1], A2 = hq[2], A3 = hq[3];
                float4 B0 = hq[4], B1 = hq[5], B2 = hq[6], B3 = hq[7];
                __builtin_amdgcn_sched_barrier(0);
                v2f p0; p0.x = xwv; p0.y = 0.f;  // xw folded into acc init
                v2f p1 = {0.f, 0.f}, p2 = {0.f, 0.f}, p3 = {0.f, 0.f};
                // stage 1: FMA A (k 0..15), reload A <- quads 8..11
                ACCQ(A0, 0); ACCQ(A1, 1); ACCQ(A2, 2); ACCQ(A3, 3);
                A0 = hq[8]; A1 = hq[9]; A2 = hq[10]; A3 = hq[11];
                __builtin_amdgcn_sched_barrier(0);
                // stage 2: FMA B (k 16..31), reload B <- quads 12..15
                ACCQ(B0, 4); ACCQ(B1, 5); ACCQ(B2, 6); ACCQ(B3, 7);
                B0 = hq[12]; B1 = hq[13]; B2 = hq[14]; B3 = hq[15];
                __builtin_amdgcn_sched_barrier(0);
                // stage 3: FMA A' (k 32..47), FMA B' (k 48..63)
                ACCQ(A0, 8);  ACCQ(A1, 9);  ACCQ(A2, 10); ACCQ(A3, 11);
                ACCQ(B0, 12); ACCQ(B1, 13); ACCQ(B2, 14); ACCQ(B3, 15);
                v2f t = (p0 + p1) + (p2 + p3);
                h = step_tanh(t.x + t.y);
                float* wr = curBase + tl * kPad;
                wr[l] = h;                 // history row (logits + next bcast)
                prevRow = wr;
            }
        } else if (ti > 0) {
            do_logits(&hbuf[(ti - 1) & 1][0][0], WdT, bdL, out,
                      orow + (ti - 1) * kT * kO, l);
        }
        __syncthreads();   // publish tile ti history / retire tile ti-1 reads
    }
    if (w == 1)
        do_logits(&hbuf[(kTiles - 1) & 1][0][0], WdT, bdL, out,
                  orow + (kS - kT) * kO, l);
}
#undef ACCQ
} // namespace

extern "C" void kernel_launch(void* const* d_in, const int* in_sizes, int n_in,
                              void* d_out, int out_size, void* d_ws, size_t ws_size,
                              hipStream_t stream) {
    (void)in_sizes; (void)n_in; (void)d_ws; (void)ws_size; (void)out_size;
    rnn_fused<<<dim3(kB), dim3(128), 0, stream>>>(
        (const int*)d_in[0], (const int*)d_in[1],
        (const float*)d_in[2], (const float*)d_in[3],
        (const float*)d_in[4], (const float*)d_in[5],
        (const float*)d_in[6], (const float*)d_in[7],
        (float*)d_out);
}